// Round 7
// baseline (865.721 us; speedup 1.0000x reference)
//
#include <hip/hip_runtime.h>
#include <hip/hip_bf16.h>

// GCN: norm -> [agg,W1,relu] -> [W2,agg,relu] -> [W3,agg] -> LN
// R2: bf16 hi/lo 3-term MFMA GEMM (16x16x32).
// R4: panel-blocked aggregation: gather tensors stored slab-major
//     [panel][node][16f] so each panel's slab (3.2MB) is L2-resident per XCD.
//     Wave=node, lanes=[edge4][feat16], shfl-reduce. LN is a separate
//     streaming pass.
// R5/R6/R7: resubmits (bench infra failures — no data); code re-audited.

#define BLK 256

typedef __attribute__((ext_vector_type(8))) short bf16x8;
typedef __attribute__((ext_vector_type(4))) float f32x4;
typedef unsigned short u16;
typedef unsigned int u32;

__device__ inline u16 f2b_rne(float v) {
    u32 x = __float_as_uint(v);
    u32 r = (x + 0x7FFFu + ((x >> 16) & 1u)) >> 16;
    return (u16)r;
}
__device__ inline void split_bf(float v, u16& h, u16& l) {
    h = f2b_rne(v);
    float fh = __uint_as_float((u32)h << 16);
    l = f2b_rne(v - fh);
}

// ---------------- CSR build ----------------
__global__ void k_indeg(const int* __restrict__ dst, int* __restrict__ indeg, int E) {
    int e = blockIdx.x * blockDim.x + threadIdx.x;
    if (e < E) atomicAdd(&indeg[dst[e]], 1);
}

#define SCAN_T 1024
__global__ void k_scan(const int* __restrict__ indeg, int* __restrict__ rowptr, int n) {
    __shared__ int s_wsum[16];
    __shared__ int s_wpre[16];
    __shared__ int s_carry;
    int tid = threadIdx.x, lane = tid & 63, wid = tid >> 6;
    if (tid == 0) s_carry = 0;
    __syncthreads();
    const int CHUNK = SCAN_T * 8;
    for (int base = 0; base < n; base += CHUNK) {
        int idx0 = base + tid * 8;
        int loc[8]; int lsum = 0;
#pragma unroll
        for (int j = 0; j < 8; ++j) {
            int idx = idx0 + j;
            loc[j] = (idx < n) ? indeg[idx] : 0;
            lsum += loc[j];
        }
        int sc = lsum;
#pragma unroll
        for (int off = 1; off < 64; off <<= 1) {
            int t = __shfl_up(sc, off, 64);
            if (lane >= off) sc += t;
        }
        if (lane == 63) s_wsum[wid] = sc;
        __syncthreads();
        if (tid < 16) {
            int w = s_wsum[tid];
#pragma unroll
            for (int off = 1; off < 16; off <<= 1) {
                int t = __shfl_up(w, off, 64);
                if (tid >= off) w += t;
            }
            s_wpre[tid] = w;
        }
        __syncthreads();
        int excl = s_carry + (wid ? s_wpre[wid - 1] : 0) + sc - lsum;
#pragma unroll
        for (int j = 0; j < 8; ++j) {
            int idx = idx0 + j;
            if (idx < n) rowptr[idx] = excl;
            excl += loc[j];
        }
        __syncthreads();
        if (tid == 0) s_carry += s_wpre[15];
    }
    if (tid == 0) rowptr[n] = s_carry;
}

__global__ void k_fill(const int* __restrict__ src, const int* __restrict__ dst,
                       const int* __restrict__ rowptr, int* __restrict__ cursor,
                       int* __restrict__ col, int E) {
    int e = blockIdx.x * blockDim.x + threadIdx.x;
    if (e < E) {
        int d = dst[e];
        int pos = rowptr[d] + atomicAdd(&cursor[d], 1);
        col[pos] = src[e];
    }
}

__global__ void k_dinv(const int* __restrict__ indeg, float* __restrict__ dinv, int n) {
    int i = blockIdx.x * blockDim.x + threadIdx.x;
    if (i < n) dinv[i] = rsqrtf((float)indeg[i] + 1.0f);
}

// W[K][N] fp32 -> Wt[N][K] bf16 hi/lo
__global__ void k_wprep(const float* __restrict__ W, u16* __restrict__ Whi,
                        u16* __restrict__ Wlo, int K, int N) {
    int idx = blockIdx.x * blockDim.x + threadIdx.x;
    if (idx >= K * N) return;
    int nn = idx / K, kk = idx - nn * K;
    float v = W[(size_t)kk * N + nn];
    u16 h, l; split_bf(v, h, l);
    Whi[idx] = h; Wlo[idx] = l;
}

// Xs slab[8][n][16] = emb[ids[node]] * dinv[node]
__global__ void k_prescale(const float* __restrict__ emb, const int* __restrict__ ids,
                           const float* __restrict__ dinv, float* __restrict__ xs, int n) {
    int t = blockIdx.x * blockDim.x + threadIdx.x;
    if (t >= n * 32) return;
    int node = t >> 5, fq = t & 31;   // fq: float4 index 0..31
    int s = ids[node];
    float4 v = ((const float4*)emb)[(size_t)s * 32 + fq];
    float di = dinv[node];
    int panel = fq >> 2, q = fq & 3;
    ((float4*)xs)[((size_t)panel * n + node) * 4 + q] =
        make_float4(v.x*di, v.y*di, v.z*di, v.w*di);
}

// ---------------- panel-blocked aggregation --------------------------------
// input Hs: slab [NP][n][16] fp32 (one panel slab = n*64B, L2-resident)
// result r = EPI(dinv[i] * (Hs[i] + sum_nb Hs))
//   EPI 0: *dinv        EPI 1: relu(*dinv + bias)       EPI 2: *dinv + bias
// OUT 0: fp32 row-major [n][NP*16]; OUT 1: u16 hi/lo row-major.
// wave = 1 node; lanes = [esub 0..3][feat 0..15].
template<int NP, int EPI, int OUT>
__global__ __launch_bounds__(256) void k_agg_p(
        const float* __restrict__ Hs, const int* __restrict__ rowptr,
        const int* __restrict__ col, const float* __restrict__ dinv,
        const float* __restrict__ bias, float* __restrict__ outf,
        u16* __restrict__ outh, u16* __restrict__ outl, int n) {
    constexpr int NPW = 4;   // nodes per wave (sequential)
    int panel = blockIdx.y;
    int lane = threadIdx.x & 63;
    int wid  = blockIdx.x * (blockDim.x >> 6) + (threadIdx.x >> 6);
    int esub = lane >> 4, fl = lane & 15;
    const float* Hp = Hs + (size_t)panel * n * 16;
    int node0 = wid * NPW;
    for (int ni = 0; ni < NPW; ++ni) {
        int node = node0 + ni;
        if (node >= n) break;
        int beg = rowptr[node], end = rowptr[node + 1];
        float selfv = Hp[(size_t)node * 16 + fl];
        float acc = 0.f;
#pragma unroll 2
        for (int e = beg; e < end; e += 4) {
            int ee = e + esub;
            int idx = col[min(ee, end - 1)];
            float v = Hp[(size_t)idx * 16 + fl];
            acc += (ee < end) ? v : 0.f;
        }
        acc += __shfl_xor(acc, 16, 64);
        acc += __shfl_xor(acc, 32, 64);
        acc += selfv;
        float di = dinv[node];
        int feat = panel * 16 + fl;
        float r;
        if constexpr (EPI == 0)      r = acc * di;
        else if constexpr (EPI == 1) r = fmaxf(fmaf(acc, di, bias[feat]), 0.f);
        else                         r = fmaf(acc, di, bias[feat]);
        if (esub == 0) {
            if constexpr (OUT == 0) {
                outf[(size_t)node * (NP * 16) + feat] = r;
            } else {
                u16 h, l; split_bf(r, h, l);
                outh[(size_t)node * (NP * 16) + feat] = h;
                outl[(size_t)node * (NP * 16) + feat] = l;
            }
        }
    }
}

// streaming LayerNorm over T[n][128] -> out
__global__ __launch_bounds__(BLK) void k_ln(const float* __restrict__ T,
        const float* __restrict__ gamma, const float* __restrict__ beta,
        float* __restrict__ out, int n) {
    int gt = blockIdx.x * blockDim.x + threadIdx.x;
    int node = gt >> 6, lane = gt & 63;
    if (node >= n) return;
    float2 t = ((const float2*)T)[(size_t)node * 64 + lane];
    float s = t.x + t.y, sq = t.x*t.x + t.y*t.y;
#pragma unroll
    for (int off = 32; off >= 1; off >>= 1) {
        s  += __shfl_xor(s, off, 64);
        sq += __shfl_xor(sq, off, 64);
    }
    float mu  = s * (1.0f / 128.0f);
    float var = sq * (1.0f / 128.0f) - mu * mu;
    float inv = rsqrtf(var + 1e-5f);
    int f0 = lane * 2;
    float2 o;
    o.x = fmaf((t.x - mu) * inv, gamma[f0],     beta[f0]);
    o.y = fmaf((t.y - mu) * inv, gamma[f0 + 1], beta[f0 + 1]);
    ((float2*)out)[(size_t)node * 64 + lane] = o;
}

// ---------------- bf16x3 MFMA GEMM -----------------------------------------
// C = Ahi@Bhi + Ahi@Blo + Alo@Bhi (~fp32).  A:[M][K] pair, B: Wt[N][K] pair.
// Tile 128x128, BK=64, 4 waves x 64x64. LDS XOR-swizzled (write+read).
// EPI 0: relu(x+bias[n]) -> hi/lo row-major.  EPI 1: x*dinv[m] -> fp32 SLAB
// [nn>>4][M][nn&15] (feeds panel agg).
template<int EPI>
__global__ __launch_bounds__(256) void k_gemm_bf3(
        const u16* __restrict__ Ahi, const u16* __restrict__ Alo,
        const u16* __restrict__ Bhi, const u16* __restrict__ Blo,
        const float* __restrict__ bias, const float* __restrict__ dinv,
        float* __restrict__ Cf, u16* __restrict__ Chi, u16* __restrict__ Clo,
        int M, int N, int K) {
    __shared__ u16 sA[2][128 * 64];
    __shared__ u16 sB[2][128 * 64];
    int m0 = blockIdx.x * 128;
    int n0 = blockIdx.y * 128;
    int tid = threadIdx.x;
    int lane = tid & 63, wid = tid >> 6;
    int wm = wid >> 1, wn = wid & 1;
    int r16 = lane & 15, kg = lane >> 4;
    f32x4 acc[4][4] = {};
    for (int k0 = 0; k0 < K; k0 += 64) {
        for (int c = tid; c < 1024; c += 256) {
            int row = c >> 3, slot = c & 7;
            int sl = slot ^ (row & 7);
            int gm = m0 + row;
            uint4 vh = make_uint4(0u,0u,0u,0u), vl = vh;
            if (gm < M) {
                size_t g = (size_t)gm * K + k0 + slot * 8;
                vh = *(const uint4*)(Ahi + g);
                vl = *(const uint4*)(Alo + g);
            }
            *(uint4*)&sA[0][row * 64 + sl * 8] = vh;
            *(uint4*)&sA[1][row * 64 + sl * 8] = vl;
            size_t gb = (size_t)(n0 + row) * K + k0 + slot * 8;
            *(uint4*)&sB[0][row * 64 + sl * 8] = *(const uint4*)(Bhi + gb);
            *(uint4*)&sB[1][row * 64 + sl * 8] = *(const uint4*)(Blo + gb);
        }
        __syncthreads();
#pragma unroll
        for (int kk = 0; kk < 2; ++kk) {
            bf16x8 ah[4], al[4], bh[4], bl[4];
#pragma unroll
            for (int f = 0; f < 4; ++f) {
                int ar = wm * 64 + f * 16 + r16;
                int asl = (kk * 4 + kg) ^ (ar & 7);
                ah[f] = *(const bf16x8*)&sA[0][ar * 64 + asl * 8];
                al[f] = *(const bf16x8*)&sA[1][ar * 64 + asl * 8];
                int br = wn * 64 + f * 16 + r16;
                int bsl = (kk * 4 + kg) ^ (br & 7);
                bh[f] = *(const bf16x8*)&sB[0][br * 64 + bsl * 8];
                bl[f] = *(const bf16x8*)&sB[1][br * 64 + bsl * 8];
            }
#pragma unroll
            for (int i = 0; i < 4; ++i)
#pragma unroll
            for (int j = 0; j < 4; ++j) {
                acc[i][j] = __builtin_amdgcn_mfma_f32_16x16x32_bf16(ah[i], bh[j], acc[i][j], 0, 0, 0);
                acc[i][j] = __builtin_amdgcn_mfma_f32_16x16x32_bf16(ah[i], bl[j], acc[i][j], 0, 0, 0);
                acc[i][j] = __builtin_amdgcn_mfma_f32_16x16x32_bf16(al[i], bh[j], acc[i][j], 0, 0, 0);
            }
        }
        __syncthreads();
    }
    // C/D layout: col=lane&15, row=(lane>>4)*4+reg
#pragma unroll
    for (int i = 0; i < 4; ++i) {
#pragma unroll
        for (int j = 0; j < 4; ++j) {
            int nn = n0 + wn * 64 + j * 16 + r16;
            float bv = 0.f;
            if constexpr (EPI == 0) bv = bias[nn];
#pragma unroll
            for (int r = 0; r < 4; ++r) {
                int mm = m0 + wm * 64 + i * 16 + kg * 4 + r;
                if (mm >= M) continue;
                float x = acc[i][j][r];
                if constexpr (EPI == 0) {
                    x = fmaxf(x + bv, 0.f);
                    u16 h, l; split_bf(x, h, l);
                    size_t o = (size_t)mm * N + nn;
                    Chi[o] = h; Clo[o] = l;
                } else {
                    x *= dinv[mm];
                    Cf[((size_t)(nn >> 4) * M + mm) * 16 + (nn & 15)] = x;
                }
            }
        }
    }
}

static inline size_t align256(size_t x) { return (x + 255) & ~(size_t)255; }

extern "C" void kernel_launch(void* const* d_in, const int* in_sizes, int n_in,
                              void* d_out, int out_size, void* d_ws, size_t ws_size,
                              hipStream_t stream) {
    const int*   node_ids = (const int*)  d_in[0];
    const int*   ei       = (const int*)  d_in[1];
    const float* emb      = (const float*)d_in[2];
    const float* W1       = (const float*)d_in[3];
    const float* b1       = (const float*)d_in[4];
    const float* W2       = (const float*)d_in[5];
    const float* b2       = (const float*)d_in[6];
    const float* W3       = (const float*)d_in[7];
    const float* b3       = (const float*)d_in[8];
    const float* gamma    = (const float*)d_in[9];
    const float* beta     = (const float*)d_in[10];
    float* out = (float*)d_out;

    const int N = in_sizes[0];
    const int E = in_sizes[1] / 2;
    const int* esrc = ei;
    const int* edst = ei + E;

    char* p = (char*)d_ws;
    size_t off = 0;
    int*   indeg  = (int*)(p + off);   off = align256(off + (size_t)N * 4);
    int*   rowptr = (int*)(p + off);   off = align256(off + (size_t)(N + 1) * 4);
    int*   cursor = (int*)(p + off);   off = align256(off + (size_t)N * 4);
    float* dinv   = (float*)(p + off); off = align256(off + (size_t)N * 4);
    int*   col    = (int*)(p + off);   off = align256(off + (size_t)E * 4);
    u16* W1thi = (u16*)(p + off); off = align256(off + 256 * 128 * 2);
    u16* W1tlo = (u16*)(p + off); off = align256(off + 256 * 128 * 2);
    u16* W2thi = (u16*)(p + off); off = align256(off + 256 * 256 * 2);
    u16* W2tlo = (u16*)(p + off); off = align256(off + 256 * 256 * 2);
    u16* W3thi = (u16*)(p + off); off = align256(off + 128 * 256 * 2);
    u16* W3tlo = (u16*)(p + off); off = align256(off + 128 * 256 * 2);
    char* P1 = p + off; off = align256(off + (size_t)N * 256 * 4);  // 51.2MB
    char* P2 = p + off; off = align256(off + (size_t)N * 256 * 4);  // 51.2MB

    // P1: Xslab[8][N][16] -> H1 hi/lo rowmajor -> X2 hi/lo rowmajor -> T3
    // P2: A1 hi/lo rowmajor -> G2 slab[16][N][16] -> G3 slab[8][N][16]
    float* Xslab = (float*)P1;
    u16*   H1hi  = (u16*)P1;
    u16*   H1lo  = (u16*)(P1 + (size_t)N * 256 * 2);
    u16*   X2hi  = H1hi;
    u16*   X2lo  = H1lo;
    float* T3    = (float*)P1;
    u16*   A1hi  = (u16*)P2;
    u16*   A1lo  = (u16*)(P2 + (size_t)N * 128 * 2);
    float* G2s   = (float*)P2;
    float* G3s   = (float*)P2;

    hipMemsetAsync(indeg, 0, (size_t)N * 4, stream);
    hipMemsetAsync(cursor, 0, (size_t)N * 4, stream);

    int eb = (E + BLK - 1) / BLK;
    k_indeg<<<eb, BLK, 0, stream>>>(edst, indeg, E);
    k_scan<<<1, SCAN_T, 0, stream>>>(indeg, rowptr, N);
    k_fill<<<eb, BLK, 0, stream>>>(esrc, edst, rowptr, cursor, col, E);
    k_dinv<<<(N + BLK - 1) / BLK, BLK, 0, stream>>>(indeg, dinv, N);

    k_wprep<<<(128 * 256 + 255) / 256, 256, 0, stream>>>(W1, W1thi, W1tlo, 128, 256);
    k_wprep<<<(256 * 256 + 255) / 256, 256, 0, stream>>>(W2, W2thi, W2tlo, 256, 256);
    k_wprep<<<(256 * 128 + 255) / 256, 256, 0, stream>>>(W3, W3thi, W3tlo, 256, 128);

    int mg = (N + 127) / 128;
    int ab = (N + 15) / 16;      // agg blocks per panel: 4 waves x 4 nodes

    k_prescale<<<(N * 32 + BLK - 1) / BLK, BLK, 0, stream>>>(emb, node_ids, dinv, Xslab, N);
    k_agg_p<8, 0, 1><<<dim3(ab, 8), BLK, 0, stream>>>(
        Xslab, rowptr, col, dinv, nullptr, nullptr, A1hi, A1lo, N);
    k_gemm_bf3<0><<<dim3(mg, 2), 256, 0, stream>>>(
        A1hi, A1lo, W1thi, W1tlo, b1, nullptr, nullptr, H1hi, H1lo, N, 256, 128);
    k_gemm_bf3<1><<<dim3(mg, 2), 256, 0, stream>>>(
        H1hi, H1lo, W2thi, W2tlo, nullptr, dinv, G2s, nullptr, nullptr, N, 256, 256);
    k_agg_p<16, 1, 1><<<dim3(ab, 16), BLK, 0, stream>>>(
        G2s, rowptr, col, dinv, b2, nullptr, X2hi, X2lo, N);
    k_gemm_bf3<1><<<dim3(mg, 1), 256, 0, stream>>>(
        X2hi, X2lo, W3thi, W3tlo, nullptr, dinv, G3s, nullptr, nullptr, N, 128, 256);
    k_agg_p<8, 2, 0><<<dim3(ab, 8), BLK, 0, stream>>>(
        G3s, rowptr, col, dinv, b3, T3, nullptr, nullptr, N);
    k_ln<<<(N * 64 + BLK - 1) / BLK, BLK, 0, stream>>>(T3, gamma, beta, out, N);
}